// Round 20
// baseline (505.903 us; speedup 1.0000x reference)
//
#include <hip/hip_runtime.h>
#include <hip/hip_bf16.h>
#include <math.h>

typedef float f32x4 __attribute__((ext_vector_type(4)));
typedef short bf16x8 __attribute__((ext_vector_type(8)));
typedef short bf16x4 __attribute__((ext_vector_type(4)));

#define AS1 __attribute__((address_space(1)))
#define AS3 __attribute__((address_space(3)))

__device__ __forceinline__ short f2bf(float f) {
    unsigned u = __float_as_uint(f);
    unsigned r = (u + 0x7fffu + ((u >> 16) & 1u)) >> 16;
    return (short)r;
}
__device__ __forceinline__ float bf2f(short s) {
    return __uint_as_float(((unsigned)(unsigned short)s) << 16);
}
__device__ __forceinline__ void gld16(const void* g, void* l) {
    __builtin_amdgcn_global_load_lds((const AS1 unsigned int*)g, (AS3 unsigned int*)l, 16, 0, 0);
}

// stage a [128][64]-short tile (global row stride 256 shorts) into linear LDS
// with XOR-swizzled SOURCE (slot ^= row&7); reads use the matching swizzle.
// 256-thread version (4 chunks/thread).
__device__ __forceinline__ void stage128x64(const short* __restrict__ g,
                                            short* lds, int t) {
    int w = t >> 6, l = t & 63;
    #pragma unroll
    for (int j = 0; j < 4; ++j) {
        int ii = j * 4 + w;
        int row = ii * 8 + (l >> 3);
        int slot = (l & 7) ^ (row & 7);
        gld16(g + row * 256 + slot * 8, lds + ii * 512);
    }
}

// ---------------- kernel 0+1 merged: weight transpose (bid<768) + pe/x transpose
__global__ __launch_bounds__(256) void k_prep(const float* __restrict__ x,
                                              const float* __restrict__ Wq,
                                              const float* __restrict__ Wk,
                                              const float* __restrict__ Wv,
                                              short* __restrict__ xt,
                                              short* __restrict__ Wt) {
    int bidx = blockIdx.x;              // 1280 = 768 wt + 512 pe
    if (bidx < 768) {
        int wsel = bidx >> 8, n = bidx & 255, k = threadIdx.x;
        const float* W = (wsel == 0) ? Wq : (wsel == 1) ? Wk : Wv;
        Wt[(wsel * 256 + n) * 256 + k] = f2bf(W[k * 256 + n]);
        return;
    }
    int bid = bidx - 768;               // 512 = 4 b * 128 pblocks(32)
    int b = bid >> 7;
    int pb = bid & 127;
    __shared__ __align__(16) float tile[256][33];
    __shared__ __align__(16) float pew[128][32];
    __shared__ __align__(16) float peh[128];
    int t = threadIdx.x;
    const float c1 = 0.14391156f;       // ln(10000)/64
    int wbase = (pb & 1) * 32;
    int hpos = pb >> 1;
    #pragma unroll
    for (int j = 0; j < 16; ++j) {
        int idx = t + j * 256;          // < 4096
        int c = idx >> 5, pp = idx & 31;
        int i = c >> 1;
        float d = expf(-(float)i * c1);
        float arg = (float)(wbase + pp) * d;
        pew[c][pp] = (c & 1) ? cosf(arg) : sinf(arg);
    }
    if (t < 128) {
        int i = t >> 1;
        float d = expf(-(float)i * c1);
        float arg = (float)hpos * d;
        peh[t] = (t & 1) ? cosf(arg) : sinf(arg);
    }
    int p0 = pb * 32;
    #pragma unroll
    for (int j = 0; j < 32; ++j) {
        int c = j * 8 + (t >> 5);
        int pp = t & 31;
        tile[c][pp] = x[((b * 256 + c) << 12) + p0 + pp];
    }
    __syncthreads();
    int pp = t >> 3, cseg = t & 7;
    int p = p0 + pp;
    short* dst = xt + (((b << 12) + p) << 8) + (cseg << 5);
    #pragma unroll
    for (int j = 0; j < 4; ++j) {
        bf16x8 v;
        #pragma unroll
        for (int e = 0; e < 8; ++e) {
            int c = cseg * 32 + j * 8 + e;
            float pe = (c < 128) ? pew[c][pp] : peh[c - 128];
            v[e] = f2bf(tile[c][pp] + pe);
        }
        ((bf16x8*)dst)[j] = v;
    }
}

// ---------------- kernel 2: LDS-staged projections (m97-style K-loop).
// Q = (xt@Wq)*0.0625, K = xt@Wk, V^T.
__global__ __launch_bounds__(256, 4) void k_proj(const short* __restrict__ xt,
                                                 const short* __restrict__ Wt,
                                                 short* __restrict__ Q,
                                                 short* __restrict__ K,
                                                 short* __restrict__ VT) {
    int id = blockIdx.x;                // 768 = 4b * 32mt * 2nt * 3w
    int wsel = id % 3; id /= 3;
    int nt = id & 1;  id >>= 1;
    int mt = id & 31; int b = id >> 5;
    int t = threadIdx.x, l = t & 63, w = t >> 6;
    int lr = l & 15, lg = l >> 4;
    int wr = w >> 1, wc = w & 1;        // wave sub-tile: 64m x 64n
    __shared__ __align__(16) short Xa[128 * 64];
    __shared__ __align__(16) short Wa[128 * 64];
    const short* Xg = xt + (((size_t)b << 12) + mt * 128) * 256;
    const short* Wg = Wt + ((size_t)wsel * 256 + nt * 128) * 256;
    f32x4 acc[4][4] = {};

    #pragma unroll
    for (int ks = 0; ks < 4; ++ks) {
        stage128x64(Xg + ks * 64, Xa, t);
        stage128x64(Wg + ks * 64, Wa, t);
        __syncthreads();
        #pragma unroll
        for (int s = 0; s < 2; ++s) {
            bf16x8 af[4], bw[4];
            #pragma unroll
            for (int ms = 0; ms < 4; ++ms) {
                int row = wr * 64 + ms * 16 + lr;
                af[ms] = *(const bf16x8*)(Xa + row * 64 + (((s * 4 + lg) ^ (row & 7)) << 3));
            }
            #pragma unroll
            for (int fn = 0; fn < 4; ++fn) {
                int row = wc * 64 + fn * 16 + lr;
                bw[fn] = *(const bf16x8*)(Wa + row * 64 + (((s * 4 + lg) ^ (row & 7)) << 3));
            }
            #pragma unroll
            for (int ms = 0; ms < 4; ++ms)
                #pragma unroll
                for (int fn = 0; fn < 4; ++fn)
                    acc[ms][fn] = __builtin_amdgcn_mfma_f32_16x16x32_bf16(af[ms], bw[fn], acc[ms][fn], 0, 0, 0);
        }
        __syncthreads();
    }

    int m0 = mt * 128 + wr * 64;
    int n0 = nt * 128 + wc * 64;
    if (wsel < 2) {
        float scl = (wsel == 0) ? 0.0625f : 1.0f;
        short* dst = (wsel == 0) ? Q : K;
        #pragma unroll
        for (int ms = 0; ms < 4; ++ms)
            #pragma unroll
            for (int fn = 0; fn < 4; ++fn)
                #pragma unroll
                for (int r = 0; r < 4; ++r) {
                    int m = m0 + ms * 16 + lg * 4 + r;
                    int n = n0 + fn * 16 + lr;
                    dst[((b << 12) + m) * 256 + n] = f2bf(acc[ms][fn][r] * scl);
                }
    } else {
        #pragma unroll
        for (int ms = 0; ms < 4; ++ms)
            #pragma unroll
            for (int fn = 0; fn < 4; ++fn) {
                int n = n0 + fn * 16 + lr;
                int m = m0 + ms * 16 + lg * 4;
                bf16x4 v;
                #pragma unroll
                for (int r = 0; r < 4; ++r) v[r] = f2bf(acc[ms][fn][r]);
                *(bf16x4*)(VT + ((b * 256 + n) << 12) + m) = v;
            }
    }
}

// ---------------- k_E v12: 256k x 256q tile, 1024 threads (16 waves of 64x64),
// 2-barrier K-loop. Barrier drains per FLOP halved again vs round-18; LDS 68 KB
// -> 2 blocks/CU x 16 waves = 32 waves/CU (8/SIMD) iff VGPR stays <= 64
// (launch_bounds(1024,8) pins it; per-thread code identical to the proven v11).
__global__ __launch_bounds__(1024, 8) void k_E(const short* __restrict__ Qm,
                                               const short* __restrict__ Km,
                                               short* __restrict__ E,
                                               float* __restrict__ pl) {
    int o = blockIdx.x;                 // 1024 = 4b * 16kt * 16qt
    int bid = (o & 7) * 128 + (o >> 3); // XCD swizzle (1024 % 8 == 0, bijective)
    int qt = bid & 15, kt = (bid >> 4) & 15, b = bid >> 8;
    int t = threadIdx.x, l = t & 63;
    int w = t >> 6;                     // 16 waves
    int wrk = w & 3, wcq = w >> 2;      // wave sub-tile: 64k x 64q (4 x 4 waves)
    int lr = l & 15, lg = l >> 4;
    __shared__ __align__(16) short Ka[256 * 64];   // 32 KB
    __shared__ __align__(16) short Qa[256 * 64];   // 32 KB
    __shared__ float plds[4 * 256];                // 4 KB
    const short* Kg = Km + (((size_t)b << 12) + kt * 256) * 256;
    const short* Qg = Qm + (((size_t)b << 12) + qt * 256) * 256;
    f32x4 acc[4][4] = {};

    #pragma unroll
    for (int ks = 0; ks < 4; ++ks) {
        // K tile [256][64]: 2048 chunks, 2/thread
        #pragma unroll
        for (int j = 0; j < 2; ++j) {
            int idx = j * 1024 + t;
            int row = idx >> 3;
            int slot = (idx & 7) ^ (row & 7);
            gld16(Kg + ks * 64 + row * 256 + slot * 8, Ka + idx * 8);
        }
        // Q tile [256][64]: 2048 chunks, 2/thread
        #pragma unroll
        for (int j = 0; j < 2; ++j) {
            int idx = j * 1024 + t;
            int row = idx >> 3;
            int slot = (idx & 7) ^ (row & 7);
            gld16(Qg + ks * 64 + row * 256 + slot * 8, Qa + idx * 8);
        }
        __syncthreads();
        #pragma unroll
        for (int s = 0; s < 2; ++s) {
            bf16x8 a[4], bq[4];
            #pragma unroll
            for (int mk = 0; mk < 4; ++mk) {
                int row = wrk * 64 + mk * 16 + lr;
                a[mk] = *(const bf16x8*)(Ka + row * 64 + (((s * 4 + lg) ^ (row & 7)) << 3));
            }
            #pragma unroll
            for (int nq = 0; nq < 4; ++nq) {
                int row = wcq * 64 + nq * 16 + lr;
                bq[nq] = *(const bf16x8*)(Qa + row * 64 + (((s * 4 + lg) ^ (row & 7)) << 3));
            }
            #pragma unroll
            for (int mk = 0; mk < 4; ++mk)
                #pragma unroll
                for (int nq = 0; nq < 4; ++nq)
                    acc[mk][nq] = __builtin_amdgcn_mfma_f32_16x16x32_bf16(a[mk], bq[nq], acc[mk][nq], 0, 0, 0);
        }
        __syncthreads();
    }

    // epilogue: e = expf(acc) (scale pre-folded into Q), RNE pack, store,
    // and column (q) partial sums
    int k0 = kt * 256 + wrk * 64;
    int q0 = qt * 256 + wcq * 64;
    float psum[4][4];                   // [mk][r]
    #pragma unroll
    for (int mk = 0; mk < 4; ++mk) {
        float ps0 = 0.f, ps1 = 0.f, ps2 = 0.f, ps3 = 0.f;
        #pragma unroll
        for (int nq = 0; nq < 4; ++nq) {
            int q = q0 + nq * 16 + lr;
            float e0 = __expf(acc[mk][nq][0]);
            float e1 = __expf(acc[mk][nq][1]);
            float e2 = __expf(acc[mk][nq][2]);
            float e3 = __expf(acc[mk][nq][3]);
            ps0 += e0; ps1 += e1; ps2 += e2; ps3 += e3;
            bf16x4 ev;
            ev[0] = f2bf(e0); ev[1] = f2bf(e1); ev[2] = f2bf(e2); ev[3] = f2bf(e3);
            *(bf16x4*)(E + (((size_t)b << 12) + q) * 4096 + k0 + mk * 16 + lg * 4) = ev;
        }
        psum[mk][0] = ps0; psum[mk][1] = ps1; psum[mk][2] = ps2; psum[mk][3] = ps3;
    }
    #pragma unroll
    for (int mk = 0; mk < 4; ++mk)
        #pragma unroll
        for (int r = 0; r < 4; ++r) {
            float v = psum[mk][r];
            v += __shfl_xor(v, 1);
            v += __shfl_xor(v, 2);
            v += __shfl_xor(v, 4);
            v += __shfl_xor(v, 8);
            psum[mk][r] = v;
        }
    // wave (wrk,wcq) owns plds[wcq][wrk*64 .. wrk*64+63]
    if (lr == 0) {
        #pragma unroll
        for (int mk = 0; mk < 4; ++mk)
            #pragma unroll
            for (int r = 0; r < 4; ++r)
                plds[wcq * 256 + wrk * 64 + mk * 16 + lg * 4 + r] = psum[mk][r];
    }
    __syncthreads();
    if (t < 256) {
        float s = plds[t] + plds[256 + t] + plds[512 + t] + plds[768 + t];
        pl[(b * 16 + qt) * 4096 + kt * 256 + t] = s;
    }
}

// k_lred: rl[b][k] = 1 / sum_qt pl[b][qt][k]   (16 q-tiles of 256)
__global__ void k_lred(const float* __restrict__ pl, float* __restrict__ rl) {
    int gid = blockIdx.x * 256 + threadIdx.x;   // 16384
    float s = 0.f;
    int b = gid >> 12, k = gid & 4095;
    #pragma unroll
    for (int qt = 0; qt < 16; ++qt) s += pl[(b * 16 + qt) * 4096 + k];
    rl[gid] = 1.0f / s;
}

// k_vn: Vnt[b][c][k] = VT[b][c][k] * rl[b][k]
__global__ void k_vn(const short* __restrict__ VT, const float* __restrict__ rl,
                     short* __restrict__ Vnt) {
    int gid = blockIdx.x * 256 + threadIdx.x;   // 524288
    int idx8 = gid * 8;
    int b = idx8 >> 20;
    int rem = idx8 & 1048575;
    int k = rem & 4095;
    bf16x8 v = *(const bf16x8*)(VT + idx8);
    const float* rb = rl + (b << 12) + k;
    f32x4 r0 = *(const f32x4*)(rb);
    f32x4 r1 = *(const f32x4*)(rb + 4);
    bf16x8 oo;
    #pragma unroll
    for (int e = 0; e < 8; ++e) {
        float f = bf2f(v[e]);
        float rr = (e < 4) ? r0[e] : r1[e - 4];
        oo[e] = f2bf(f * rr);
    }
    *(bf16x8*)(Vnt + idx8) = oo;
}

// ---------------- k_pv v9 (round-19 proven): BK=128, 64q x 128c block, 4 waves
// of 32q x 64c, 16-slot-row swizzle, 48 KB LDS, grid 512, pair mapping.
__global__ __launch_bounds__(256) void k_pv(const short* __restrict__ E,
                                            const short* __restrict__ Vnt,
                                            float* __restrict__ out) {
    int o = blockIdx.x;                 // 512
    int ct = o >> 8;                    // c-half
    int r = o & 255;
    int b = r >> 6, qt = r & 63;
    int t = threadIdx.x, l = t & 63, w = t >> 6;
    int wq = w >> 1, wc = w & 1;        // wave: 32 q x 64 c
    int lr = l & 15, lg = l >> 4;
    int q0 = qt * 64, c0 = ct * 128;
    __shared__ __align__(16) short Ea[64 * 128];   // 16 KB
    __shared__ __align__(16) short Va[128 * 128];  // 32 KB
    const short* Eg = E + (((size_t)b << 12) + q0) * 4096;
    const short* Vg = Vnt + ((size_t)(b * 256 + c0)) * 4096;
    f32x4 acc[2][4] = {};

    for (int kc = 0; kc < 4096; kc += 128) {
        #pragma unroll
        for (int j = 0; j < 4; ++j) {
            int idx = j * 256 + t;
            int row = idx >> 4;
            int slot = (idx & 15) ^ (row & 15);
            gld16(Eg + kc + (size_t)row * 4096 + slot * 8, Ea + idx * 8);
        }
        #pragma unroll
        for (int j = 0; j < 8; ++j) {
            int idx = j * 256 + t;
            int row = idx >> 4;
            int slot = (idx & 15) ^ (row & 15);
            gld16(Vg + kc + (size_t)row * 4096 + slot * 8, Va + idx * 8);
        }
        __syncthreads();
        #pragma unroll
        for (int s = 0; s < 4; ++s) {
            bf16x8 Af[2], Bf[4];
            #pragma unroll
            for (int mq = 0; mq < 2; ++mq) {
                int row = wq * 32 + mq * 16 + lr;
                Af[mq] = *(const bf16x8*)(Ea + row * 128 + (((s * 4 + lg) ^ (row & 15)) << 3));
            }
            #pragma unroll
            for (int nc = 0; nc < 4; ++nc) {
                int row = wc * 64 + nc * 16 + lr;
                Bf[nc] = *(const bf16x8*)(Va + row * 128 + (((s * 4 + lg) ^ (row & 15)) << 3));
            }
            #pragma unroll
            for (int mq = 0; mq < 2; ++mq)
                #pragma unroll
                for (int nc = 0; nc < 4; ++nc)
                    acc[mq][nc] = __builtin_amdgcn_mfma_f32_16x16x32_bf16(Af[mq], Bf[nc], acc[mq][nc], 0, 0, 0);
        }
        __syncthreads();
    }
    #pragma unroll
    for (int mq = 0; mq < 2; ++mq)
        #pragma unroll
        for (int nc = 0; nc < 4; ++nc) {
            int c = c0 + wc * 64 + nc * 16 + lr;
            int q = q0 + wq * 32 + mq * 16 + lg * 4;
            *(f32x4*)(out + (((size_t)b << 8) + c) * 4096 + q) = acc[mq][nc];
        }
}

extern "C" void kernel_launch(void* const* d_in, const int* in_sizes, int n_in,
                              void* d_out, int out_size, void* d_ws, size_t ws_size,
                              hipStream_t stream) {
    const float* x  = (const float*)d_in[0];
    const float* Wq = (const float*)d_in[1];
    const float* Wk = (const float*)d_in[2];
    const float* Wv = (const float*)d_in[3];

    char* p = (char*)d_ws;
    short* xt  = (short*)p; p += 4 * 4096 * 256 * 2;   // 8 MB
    short* Wt  = (short*)p; p += 3 * 256 * 256 * 2;    // 384 KB
    short* Qm  = (short*)p; p += 4 * 4096 * 256 * 2;
    short* Km  = (short*)p; p += 4 * 4096 * 256 * 2;
    short* VT  = (short*)p; p += 4 * 4096 * 256 * 2;
    short* E   = (short*)p; p += (size_t)4 * 4096 * 4096 * 2;  // 134.2 MB
    float* pl  = (float*)p; p += 4 * 32 * 4096 * 4;            // 2 MB (16 used)
    float* rl  = (float*)p; p += 4 * 4096 * 4;                 // 64 KB
    short* Vnt = (short*)p; p += 4 * 4096 * 256 * 2;           // 8 MB

    float* out = (float*)d_out;

    k_prep <<<1280, 256, 0, stream>>>(x, Wq, Wk, Wv, xt, Wt);
    k_proj <<<768, 256, 0, stream>>>(xt, Wt, Qm, Km, VT);
    k_E    <<<1024, 1024, 0, stream>>>(Qm, Km, E, pl);
    k_lred <<<64,   256, 0, stream>>>(pl, rl);
    k_vn   <<<2048, 256, 0, stream>>>(VT, rl, Vnt);
    k_pv   <<<512,  256, 0, stream>>>(E, Vnt, out);
}

// Round 21
// 155.425 us; speedup vs baseline: 3.2550x; 3.2550x over previous
//
#include <hip/hip_runtime.h>
#include <hip/hip_bf16.h>
#include <math.h>

typedef float f32x4 __attribute__((ext_vector_type(4)));
typedef short bf16x8 __attribute__((ext_vector_type(8)));
typedef short bf16x4 __attribute__((ext_vector_type(4)));

#define AS1 __attribute__((address_space(1)))
#define AS3 __attribute__((address_space(3)))

__device__ __forceinline__ short f2bf(float f) {
    unsigned u = __float_as_uint(f);
    unsigned r = (u + 0x7fffu + ((u >> 16) & 1u)) >> 16;
    return (short)r;
}
__device__ __forceinline__ float bf2f(short s) {
    return __uint_as_float(((unsigned)(unsigned short)s) << 16);
}
__device__ __forceinline__ void gld16(const void* g, void* l) {
    __builtin_amdgcn_global_load_lds((const AS1 unsigned int*)g, (AS3 unsigned int*)l, 16, 0, 0);
}

// stage a [128][64]-short tile (global row stride 256 shorts) into linear LDS
// with XOR-swizzled SOURCE (slot ^= row&7); reads use the matching swizzle.
// 256-thread version (4 chunks/thread).
__device__ __forceinline__ void stage128x64(const short* __restrict__ g,
                                            short* lds, int t) {
    int w = t >> 6, l = t & 63;
    #pragma unroll
    for (int j = 0; j < 4; ++j) {
        int ii = j * 4 + w;
        int row = ii * 8 + (l >> 3);
        int slot = (l & 7) ^ (row & 7);
        gld16(g + row * 256 + slot * 8, lds + ii * 512);
    }
}

// ---------------- kernel 0+1 merged: weight transpose (bid<768) + pe/x transpose
__global__ __launch_bounds__(256) void k_prep(const float* __restrict__ x,
                                              const float* __restrict__ Wq,
                                              const float* __restrict__ Wk,
                                              const float* __restrict__ Wv,
                                              short* __restrict__ xt,
                                              short* __restrict__ Wt) {
    int bidx = blockIdx.x;              // 1280 = 768 wt + 512 pe
    if (bidx < 768) {
        int wsel = bidx >> 8, n = bidx & 255, k = threadIdx.x;
        const float* W = (wsel == 0) ? Wq : (wsel == 1) ? Wk : Wv;
        Wt[(wsel * 256 + n) * 256 + k] = f2bf(W[k * 256 + n]);
        return;
    }
    int bid = bidx - 768;               // 512 = 4 b * 128 pblocks(32)
    int b = bid >> 7;
    int pb = bid & 127;
    __shared__ __align__(16) float tile[256][33];
    __shared__ __align__(16) float pew[128][32];
    __shared__ __align__(16) float peh[128];
    int t = threadIdx.x;
    const float c1 = 0.14391156f;       // ln(10000)/64
    int wbase = (pb & 1) * 32;
    int hpos = pb >> 1;
    #pragma unroll
    for (int j = 0; j < 16; ++j) {
        int idx = t + j * 256;          // < 4096
        int c = idx >> 5, pp = idx & 31;
        int i = c >> 1;
        float d = expf(-(float)i * c1);
        float arg = (float)(wbase + pp) * d;
        pew[c][pp] = (c & 1) ? cosf(arg) : sinf(arg);
    }
    if (t < 128) {
        int i = t >> 1;
        float d = expf(-(float)i * c1);
        float arg = (float)hpos * d;
        peh[t] = (t & 1) ? cosf(arg) : sinf(arg);
    }
    int p0 = pb * 32;
    #pragma unroll
    for (int j = 0; j < 32; ++j) {
        int c = j * 8 + (t >> 5);
        int pp = t & 31;
        tile[c][pp] = x[((b * 256 + c) << 12) + p0 + pp];
    }
    __syncthreads();
    int pp = t >> 3, cseg = t & 7;
    int p = p0 + pp;
    short* dst = xt + (((b << 12) + p) << 8) + (cseg << 5);
    #pragma unroll
    for (int j = 0; j < 4; ++j) {
        bf16x8 v;
        #pragma unroll
        for (int e = 0; e < 8; ++e) {
            int c = cseg * 32 + j * 8 + e;
            float pe = (c < 128) ? pew[c][pp] : peh[c - 128];
            v[e] = f2bf(tile[c][pp] + pe);
        }
        ((bf16x8*)dst)[j] = v;
    }
}

// ---------------- kernel 2: LDS-staged projections (m97-style K-loop).
// Q = (xt@Wq)*0.0625, K = xt@Wk, V^T.
__global__ __launch_bounds__(256, 4) void k_proj(const short* __restrict__ xt,
                                                 const short* __restrict__ Wt,
                                                 short* __restrict__ Q,
                                                 short* __restrict__ K,
                                                 short* __restrict__ VT) {
    int id = blockIdx.x;                // 768 = 4b * 32mt * 2nt * 3w
    int wsel = id % 3; id /= 3;
    int nt = id & 1;  id >>= 1;
    int mt = id & 31; int b = id >> 5;
    int t = threadIdx.x, l = t & 63, w = t >> 6;
    int lr = l & 15, lg = l >> 4;
    int wr = w >> 1, wc = w & 1;        // wave sub-tile: 64m x 64n
    __shared__ __align__(16) short Xa[128 * 64];
    __shared__ __align__(16) short Wa[128 * 64];
    const short* Xg = xt + (((size_t)b << 12) + mt * 128) * 256;
    const short* Wg = Wt + ((size_t)wsel * 256 + nt * 128) * 256;
    f32x4 acc[4][4] = {};

    #pragma unroll
    for (int ks = 0; ks < 4; ++ks) {
        stage128x64(Xg + ks * 64, Xa, t);
        stage128x64(Wg + ks * 64, Wa, t);
        __syncthreads();
        #pragma unroll
        for (int s = 0; s < 2; ++s) {
            bf16x8 af[4], bw[4];
            #pragma unroll
            for (int ms = 0; ms < 4; ++ms) {
                int row = wr * 64 + ms * 16 + lr;
                af[ms] = *(const bf16x8*)(Xa + row * 64 + (((s * 4 + lg) ^ (row & 7)) << 3));
            }
            #pragma unroll
            for (int fn = 0; fn < 4; ++fn) {
                int row = wc * 64 + fn * 16 + lr;
                bw[fn] = *(const bf16x8*)(Wa + row * 64 + (((s * 4 + lg) ^ (row & 7)) << 3));
            }
            #pragma unroll
            for (int ms = 0; ms < 4; ++ms)
                #pragma unroll
                for (int fn = 0; fn < 4; ++fn)
                    acc[ms][fn] = __builtin_amdgcn_mfma_f32_16x16x32_bf16(af[ms], bw[fn], acc[ms][fn], 0, 0, 0);
        }
        __syncthreads();
    }

    int m0 = mt * 128 + wr * 64;
    int n0 = nt * 128 + wc * 64;
    if (wsel < 2) {
        float scl = (wsel == 0) ? 0.0625f : 1.0f;
        short* dst = (wsel == 0) ? Q : K;
        #pragma unroll
        for (int ms = 0; ms < 4; ++ms)
            #pragma unroll
            for (int fn = 0; fn < 4; ++fn)
                #pragma unroll
                for (int r = 0; r < 4; ++r) {
                    int m = m0 + ms * 16 + lg * 4 + r;
                    int n = n0 + fn * 16 + lr;
                    dst[((b << 12) + m) * 256 + n] = f2bf(acc[ms][fn][r] * scl);
                }
    } else {
        #pragma unroll
        for (int ms = 0; ms < 4; ++ms)
            #pragma unroll
            for (int fn = 0; fn < 4; ++fn) {
                int n = n0 + fn * 16 + lr;
                int m = m0 + ms * 16 + lg * 4;
                bf16x4 v;
                #pragma unroll
                for (int r = 0; r < 4; ++r) v[r] = f2bf(acc[ms][fn][r]);
                *(bf16x4*)(VT + ((b * 256 + n) << 12) + m) = v;
            }
    }
}

// ---------------- k_E v11 (round-18/19 proven): 128k x 256q tile, 512 threads
// (8 waves of 64x64), 2-barrier K-loop.
__global__ __launch_bounds__(512) void k_E(const short* __restrict__ Qm,
                                           const short* __restrict__ Km,
                                           short* __restrict__ E,
                                           float* __restrict__ pl) {
    int o = blockIdx.x;                 // 2048 = 4b * 32kt * 16qt
    int bid = (o & 7) * 256 + (o >> 3); // XCD swizzle (2048 % 8 == 0, bijective)
    int qt = bid & 15, kt = (bid >> 4) & 31, b = bid >> 9;
    int t = threadIdx.x, l = t & 63;
    int w = t >> 6;
    int wrk = w & 1, wcq = w >> 1;      // wave sub-tile: 64k x 64q (2 x 4 waves)
    int lr = l & 15, lg = l >> 4;
    __shared__ __align__(16) short Ka[128 * 64];   // 16 KB
    __shared__ __align__(16) short Qa[256 * 64];   // 32 KB
    __shared__ float plds[4 * 128];                // 2 KB
    const short* Kg = Km + (((size_t)b << 12) + kt * 128) * 256;
    const short* Qg = Qm + (((size_t)b << 12) + qt * 256) * 256;
    f32x4 acc[4][4] = {};

    #pragma unroll
    for (int ks = 0; ks < 4; ++ks) {
        #pragma unroll
        for (int j = 0; j < 2; ++j) {
            int idx = j * 512 + t;
            int row = idx >> 3;
            int slot = (idx & 7) ^ (row & 7);
            gld16(Kg + ks * 64 + row * 256 + slot * 8, Ka + idx * 8);
        }
        #pragma unroll
        for (int j = 0; j < 4; ++j) {
            int idx = j * 512 + t;
            int row = idx >> 3;
            int slot = (idx & 7) ^ (row & 7);
            gld16(Qg + ks * 64 + row * 256 + slot * 8, Qa + idx * 8);
        }
        __syncthreads();
        #pragma unroll
        for (int s = 0; s < 2; ++s) {
            bf16x8 a[4], bq[4];
            #pragma unroll
            for (int mk = 0; mk < 4; ++mk) {
                int row = wrk * 64 + mk * 16 + lr;
                a[mk] = *(const bf16x8*)(Ka + row * 64 + (((s * 4 + lg) ^ (row & 7)) << 3));
            }
            #pragma unroll
            for (int nq = 0; nq < 4; ++nq) {
                int row = wcq * 64 + nq * 16 + lr;
                bq[nq] = *(const bf16x8*)(Qa + row * 64 + (((s * 4 + lg) ^ (row & 7)) << 3));
            }
            #pragma unroll
            for (int mk = 0; mk < 4; ++mk)
                #pragma unroll
                for (int nq = 0; nq < 4; ++nq)
                    acc[mk][nq] = __builtin_amdgcn_mfma_f32_16x16x32_bf16(a[mk], bq[nq], acc[mk][nq], 0, 0, 0);
        }
        __syncthreads();
    }

    int k0 = kt * 128 + wrk * 64;
    int q0 = qt * 256 + wcq * 64;
    float psum[4][4];                   // [mk][r]
    #pragma unroll
    for (int mk = 0; mk < 4; ++mk) {
        float ps0 = 0.f, ps1 = 0.f, ps2 = 0.f, ps3 = 0.f;
        #pragma unroll
        for (int nq = 0; nq < 4; ++nq) {
            int q = q0 + nq * 16 + lr;
            float e0 = __expf(acc[mk][nq][0]);
            float e1 = __expf(acc[mk][nq][1]);
            float e2 = __expf(acc[mk][nq][2]);
            float e3 = __expf(acc[mk][nq][3]);
            ps0 += e0; ps1 += e1; ps2 += e2; ps3 += e3;
            bf16x4 ev;
            ev[0] = f2bf(e0); ev[1] = f2bf(e1); ev[2] = f2bf(e2); ev[3] = f2bf(e3);
            *(bf16x4*)(E + (((size_t)b << 12) + q) * 4096 + k0 + mk * 16 + lg * 4) = ev;
        }
        psum[mk][0] = ps0; psum[mk][1] = ps1; psum[mk][2] = ps2; psum[mk][3] = ps3;
    }
    #pragma unroll
    for (int mk = 0; mk < 4; ++mk)
        #pragma unroll
        for (int r = 0; r < 4; ++r) {
            float v = psum[mk][r];
            v += __shfl_xor(v, 1);
            v += __shfl_xor(v, 2);
            v += __shfl_xor(v, 4);
            v += __shfl_xor(v, 8);
            psum[mk][r] = v;
        }
    if (lr == 0) {
        #pragma unroll
        for (int mk = 0; mk < 4; ++mk)
            #pragma unroll
            for (int r = 0; r < 4; ++r)
                plds[wcq * 128 + wrk * 64 + mk * 16 + lg * 4 + r] = psum[mk][r];
    }
    __syncthreads();
    if (t < 128) {
        float s = plds[t] + plds[128 + t] + plds[256 + t] + plds[384 + t];
        pl[(b * 16 + qt) * 4096 + kt * 128 + t] = s;
    }
}

// k_lred: rl[b][k] = 1 / sum_qt pl[b][qt][k]   (16 q-tiles of 256)
__global__ void k_lred(const float* __restrict__ pl, float* __restrict__ rl) {
    int gid = blockIdx.x * 256 + threadIdx.x;   // 16384
    float s = 0.f;
    int b = gid >> 12, k = gid & 4095;
    #pragma unroll
    for (int qt = 0; qt < 16; ++qt) s += pl[(b * 16 + qt) * 4096 + k];
    rl[gid] = 1.0f / s;
}

// k_vn: Vnt[b][c][k] = VT[b][c][k] * rl[b][k]
__global__ void k_vn(const short* __restrict__ VT, const float* __restrict__ rl,
                     short* __restrict__ Vnt) {
    int gid = blockIdx.x * 256 + threadIdx.x;   // 524288
    int idx8 = gid * 8;
    int b = idx8 >> 20;
    int rem = idx8 & 1048575;
    int k = rem & 4095;
    bf16x8 v = *(const bf16x8*)(VT + idx8);
    const float* rb = rl + (b << 12) + k;
    f32x4 r0 = *(const f32x4*)(rb);
    f32x4 r1 = *(const f32x4*)(rb + 4);
    bf16x8 oo;
    #pragma unroll
    for (int e = 0; e < 8; ++e) {
        float f = bf2f(v[e]);
        float rr = (e < 4) ? r0[e] : r1[e - 4];
        oo[e] = f2bf(f * rr);
    }
    *(bf16x8*)(Vnt + idx8) = oo;
}

// ---------------- k_pv v9 (round-19 proven): BK=128, 64q x 128c block, 4 waves
// of 32q x 64c, 16-slot-row swizzle, 48 KB LDS, grid 512, pair mapping.
__global__ __launch_bounds__(256) void k_pv(const short* __restrict__ E,
                                            const short* __restrict__ Vnt,
                                            float* __restrict__ out) {
    int o = blockIdx.x;                 // 512
    int ct = o >> 8;                    // c-half
    int r = o & 255;
    int b = r >> 6, qt = r & 63;
    int t = threadIdx.x, l = t & 63, w = t >> 6;
    int wq = w >> 1, wc = w & 1;        // wave: 32 q x 64 c
    int lr = l & 15, lg = l >> 4;
    int q0 = qt * 64, c0 = ct * 128;
    __shared__ __align__(16) short Ea[64 * 128];   // 16 KB
    __shared__ __align__(16) short Va[128 * 128];  // 32 KB
    const short* Eg = E + (((size_t)b << 12) + q0) * 4096;
    const short* Vg = Vnt + ((size_t)(b * 256 + c0)) * 4096;
    f32x4 acc[2][4] = {};

    for (int kc = 0; kc < 4096; kc += 128) {
        #pragma unroll
        for (int j = 0; j < 4; ++j) {
            int idx = j * 256 + t;
            int row = idx >> 4;
            int slot = (idx & 15) ^ (row & 15);
            gld16(Eg + kc + (size_t)row * 4096 + slot * 8, Ea + idx * 8);
        }
        #pragma unroll
        for (int j = 0; j < 8; ++j) {
            int idx = j * 256 + t;
            int row = idx >> 4;
            int slot = (idx & 15) ^ (row & 15);
            gld16(Vg + kc + (size_t)row * 4096 + slot * 8, Va + idx * 8);
        }
        __syncthreads();
        #pragma unroll
        for (int s = 0; s < 4; ++s) {
            bf16x8 Af[2], Bf[4];
            #pragma unroll
            for (int mq = 0; mq < 2; ++mq) {
                int row = wq * 32 + mq * 16 + lr;
                Af[mq] = *(const bf16x8*)(Ea + row * 128 + (((s * 4 + lg) ^ (row & 15)) << 3));
            }
            #pragma unroll
            for (int nc = 0; nc < 4; ++nc) {
                int row = wc * 64 + nc * 16 + lr;
                Bf[nc] = *(const bf16x8*)(Va + row * 128 + (((s * 4 + lg) ^ (row & 15)) << 3));
            }
            #pragma unroll
            for (int mq = 0; mq < 2; ++mq)
                #pragma unroll
                for (int nc = 0; nc < 4; ++nc)
                    acc[mq][nc] = __builtin_amdgcn_mfma_f32_16x16x32_bf16(Af[mq], Bf[nc], acc[mq][nc], 0, 0, 0);
        }
        __syncthreads();
    }
    #pragma unroll
    for (int mq = 0; mq < 2; ++mq)
        #pragma unroll
        for (int nc = 0; nc < 4; ++nc) {
            int c = c0 + wc * 64 + nc * 16 + lr;
            int q = q0 + wq * 32 + mq * 16 + lg * 4;
            *(f32x4*)(out + (((size_t)b << 8) + c) * 4096 + q) = acc[mq][nc];
        }
}

extern "C" void kernel_launch(void* const* d_in, const int* in_sizes, int n_in,
                              void* d_out, int out_size, void* d_ws, size_t ws_size,
                              hipStream_t stream) {
    const float* x  = (const float*)d_in[0];
    const float* Wq = (const float*)d_in[1];
    const float* Wk = (const float*)d_in[2];
    const float* Wv = (const float*)d_in[3];

    char* p = (char*)d_ws;
    short* xt  = (short*)p; p += 4 * 4096 * 256 * 2;   // 8 MB
    short* Wt  = (short*)p; p += 3 * 256 * 256 * 2;    // 384 KB
    short* Qm  = (short*)p; p += 4 * 4096 * 256 * 2;
    short* Km  = (short*)p; p += 4 * 4096 * 256 * 2;
    short* VT  = (short*)p; p += 4 * 4096 * 256 * 2;
    short* E   = (short*)p; p += (size_t)4 * 4096 * 4096 * 2;  // 134.2 MB
    float* pl  = (float*)p; p += 4 * 32 * 4096 * 4;            // 2 MB (16 used)
    float* rl  = (float*)p; p += 4 * 4096 * 4;                 // 64 KB
    short* Vnt = (short*)p; p += 4 * 4096 * 256 * 2;           // 8 MB

    float* out = (float*)d_out;

    k_prep <<<1280, 256, 0, stream>>>(x, Wq, Wk, Wv, xt, Wt);
    k_proj <<<768, 256, 0, stream>>>(xt, Wt, Qm, Km, VT);
    k_E    <<<2048, 512, 0, stream>>>(Qm, Km, E, pl);
    k_lred <<<64,   256, 0, stream>>>(pl, rl);
    k_vn   <<<2048, 256, 0, stream>>>(VT, rl, Vnt);
    k_pv   <<<512,  256, 0, stream>>>(E, Vnt, out);
}

// Round 22
// 145.509 us; speedup vs baseline: 3.4768x; 1.0681x over previous
//
#include <hip/hip_runtime.h>
#include <hip/hip_bf16.h>
#include <math.h>

typedef float f32x4 __attribute__((ext_vector_type(4)));
typedef short bf16x8 __attribute__((ext_vector_type(8)));
typedef short bf16x4 __attribute__((ext_vector_type(4)));

#define AS1 __attribute__((address_space(1)))
#define AS3 __attribute__((address_space(3)))

__device__ __forceinline__ short f2bf(float f) {
    unsigned u = __float_as_uint(f);
    unsigned r = (u + 0x7fffu + ((u >> 16) & 1u)) >> 16;
    return (short)r;
}
__device__ __forceinline__ float bf2f(short s) {
    return __uint_as_float(((unsigned)(unsigned short)s) << 16);
}
__device__ __forceinline__ void gld16(const void* g, void* l) {
    __builtin_amdgcn_global_load_lds((const AS1 unsigned int*)g, (AS3 unsigned int*)l, 16, 0, 0);
}

// stage a [128][64]-short tile (global row stride 256 shorts) into linear LDS
// with XOR-swizzled SOURCE (slot ^= row&7); reads use the matching swizzle.
__device__ __forceinline__ void stage128x64(const short* __restrict__ g,
                                            short* lds, int t) {
    int w = t >> 6, l = t & 63;
    #pragma unroll
    for (int j = 0; j < 4; ++j) {
        int ii = j * 4 + w;
        int row = ii * 8 + (l >> 3);
        int slot = (l & 7) ^ (row & 7);
        gld16(g + row * 256 + slot * 8, lds + ii * 512);
    }
}

// ---------------- kernel 0+1 merged: weight transpose (bid<768) + pe/x transpose
__global__ __launch_bounds__(256) void k_prep(const float* __restrict__ x,
                                              const float* __restrict__ Wq,
                                              const float* __restrict__ Wk,
                                              const float* __restrict__ Wv,
                                              short* __restrict__ xt,
                                              short* __restrict__ Wt) {
    int bidx = blockIdx.x;              // 1280 = 768 wt + 512 pe
    if (bidx < 768) {
        int wsel = bidx >> 8, n = bidx & 255, k = threadIdx.x;
        const float* W = (wsel == 0) ? Wq : (wsel == 1) ? Wk : Wv;
        Wt[(wsel * 256 + n) * 256 + k] = f2bf(W[k * 256 + n]);
        return;
    }
    int bid = bidx - 768;               // 512 = 4 b * 128 pblocks(32)
    int b = bid >> 7;
    int pb = bid & 127;
    __shared__ __align__(16) float tile[256][33];
    __shared__ __align__(16) float pew[128][32];
    __shared__ __align__(16) float peh[128];
    int t = threadIdx.x;
    const float c1 = 0.14391156f;       // ln(10000)/64
    int wbase = (pb & 1) * 32;
    int hpos = pb >> 1;
    #pragma unroll
    for (int j = 0; j < 16; ++j) {
        int idx = t + j * 256;          // < 4096
        int c = idx >> 5, pp = idx & 31;
        int i = c >> 1;
        float d = expf(-(float)i * c1);
        float arg = (float)(wbase + pp) * d;
        pew[c][pp] = (c & 1) ? cosf(arg) : sinf(arg);
    }
    if (t < 128) {
        int i = t >> 1;
        float d = expf(-(float)i * c1);
        float arg = (float)hpos * d;
        peh[t] = (t & 1) ? cosf(arg) : sinf(arg);
    }
    int p0 = pb * 32;
    #pragma unroll
    for (int j = 0; j < 32; ++j) {
        int c = j * 8 + (t >> 5);
        int pp = t & 31;
        tile[c][pp] = x[((b * 256 + c) << 12) + p0 + pp];
    }
    __syncthreads();
    int pp = t >> 3, cseg = t & 7;
    int p = p0 + pp;
    short* dst = xt + (((b << 12) + p) << 8) + (cseg << 5);
    #pragma unroll
    for (int j = 0; j < 4; ++j) {
        bf16x8 v;
        #pragma unroll
        for (int e = 0; e < 8; ++e) {
            int c = cseg * 32 + j * 8 + e;
            float pe = (c < 128) ? pew[c][pp] : peh[c - 128];
            v[e] = f2bf(tile[c][pp] + pe);
        }
        ((bf16x8*)dst)[j] = v;
    }
}

// ---------------- kernel 2: LDS-staged projections (m97-style K-loop).
// Q = (xt@Wq)*0.0625, K = xt@Wk, V^T.
__global__ __launch_bounds__(256, 4) void k_proj(const short* __restrict__ xt,
                                                 const short* __restrict__ Wt,
                                                 short* __restrict__ Q,
                                                 short* __restrict__ K,
                                                 short* __restrict__ VT) {
    int id = blockIdx.x;                // 768 = 4b * 32mt * 2nt * 3w
    int wsel = id % 3; id /= 3;
    int nt = id & 1;  id >>= 1;
    int mt = id & 31; int b = id >> 5;
    int t = threadIdx.x, l = t & 63, w = t >> 6;
    int lr = l & 15, lg = l >> 4;
    int wr = w >> 1, wc = w & 1;        // wave sub-tile: 64m x 64n
    __shared__ __align__(16) short Xa[128 * 64];
    __shared__ __align__(16) short Wa[128 * 64];
    const short* Xg = xt + (((size_t)b << 12) + mt * 128) * 256;
    const short* Wg = Wt + ((size_t)wsel * 256 + nt * 128) * 256;
    f32x4 acc[4][4] = {};

    #pragma unroll
    for (int ks = 0; ks < 4; ++ks) {
        stage128x64(Xg + ks * 64, Xa, t);
        stage128x64(Wg + ks * 64, Wa, t);
        __syncthreads();
        #pragma unroll
        for (int s = 0; s < 2; ++s) {
            bf16x8 af[4], bw[4];
            #pragma unroll
            for (int ms = 0; ms < 4; ++ms) {
                int row = wr * 64 + ms * 16 + lr;
                af[ms] = *(const bf16x8*)(Xa + row * 64 + (((s * 4 + lg) ^ (row & 7)) << 3));
            }
            #pragma unroll
            for (int fn = 0; fn < 4; ++fn) {
                int row = wc * 64 + fn * 16 + lr;
                bw[fn] = *(const bf16x8*)(Wa + row * 64 + (((s * 4 + lg) ^ (row & 7)) << 3));
            }
            #pragma unroll
            for (int ms = 0; ms < 4; ++ms)
                #pragma unroll
                for (int fn = 0; fn < 4; ++fn)
                    acc[ms][fn] = __builtin_amdgcn_mfma_f32_16x16x32_bf16(af[ms], bw[fn], acc[ms][fn], 0, 0, 0);
        }
        __syncthreads();
    }

    int m0 = mt * 128 + wr * 64;
    int n0 = nt * 128 + wc * 64;
    if (wsel < 2) {
        float scl = (wsel == 0) ? 0.0625f : 1.0f;
        short* dst = (wsel == 0) ? Q : K;
        #pragma unroll
        for (int ms = 0; ms < 4; ++ms)
            #pragma unroll
            for (int fn = 0; fn < 4; ++fn)
                #pragma unroll
                for (int r = 0; r < 4; ++r) {
                    int m = m0 + ms * 16 + lg * 4 + r;
                    int n = n0 + fn * 16 + lr;
                    dst[((b << 12) + m) * 256 + n] = f2bf(acc[ms][fn][r] * scl);
                }
    } else {
        #pragma unroll
        for (int ms = 0; ms < 4; ++ms)
            #pragma unroll
            for (int fn = 0; fn < 4; ++fn) {
                int n = n0 + fn * 16 + lr;
                int m = m0 + ms * 16 + lg * 4;
                bf16x4 v;
                #pragma unroll
                for (int r = 0; r < 4; ++r) v[r] = f2bf(acc[ms][fn][r]);
                *(bf16x4*)(VT + ((b * 256 + n) << 12) + m) = v;
            }
    }
}

// ---------------- k_E v13: round-18/19-proven 128k x 256q bf16 loop; epilogue now
// packs E to fp8 e4m3 via v_cvt_pk_fp8_f32 (E stream halves; epilogue VALU shrinks).
__global__ __launch_bounds__(512) void k_E(const short* __restrict__ Qm,
                                           const short* __restrict__ Km,
                                           unsigned char* __restrict__ E8,
                                           float* __restrict__ pl) {
    int o = blockIdx.x;                 // 2048 = 4b * 32kt * 16qt
    int bid = (o & 7) * 256 + (o >> 3); // XCD swizzle (2048 % 8 == 0, bijective)
    int qt = bid & 15, kt = (bid >> 4) & 31, b = bid >> 9;
    int t = threadIdx.x, l = t & 63;
    int w = t >> 6;
    int wrk = w & 1, wcq = w >> 1;      // wave sub-tile: 64k x 64q (2 x 4 waves)
    int lr = l & 15, lg = l >> 4;
    __shared__ __align__(16) short Ka[128 * 64];   // 16 KB
    __shared__ __align__(16) short Qa[256 * 64];   // 32 KB
    __shared__ float plds[4 * 128];                // 2 KB
    const short* Kg = Km + (((size_t)b << 12) + kt * 128) * 256;
    const short* Qg = Qm + (((size_t)b << 12) + qt * 256) * 256;
    f32x4 acc[4][4] = {};

    #pragma unroll
    for (int ks = 0; ks < 4; ++ks) {
        #pragma unroll
        for (int j = 0; j < 2; ++j) {
            int idx = j * 512 + t;
            int row = idx >> 3;
            int slot = (idx & 7) ^ (row & 7);
            gld16(Kg + ks * 64 + row * 256 + slot * 8, Ka + idx * 8);
        }
        #pragma unroll
        for (int j = 0; j < 4; ++j) {
            int idx = j * 512 + t;
            int row = idx >> 3;
            int slot = (idx & 7) ^ (row & 7);
            gld16(Qg + ks * 64 + row * 256 + slot * 8, Qa + idx * 8);
        }
        __syncthreads();
        #pragma unroll
        for (int s = 0; s < 2; ++s) {
            bf16x8 a[4], bq[4];
            #pragma unroll
            for (int mk = 0; mk < 4; ++mk) {
                int row = wrk * 64 + mk * 16 + lr;
                a[mk] = *(const bf16x8*)(Ka + row * 64 + (((s * 4 + lg) ^ (row & 7)) << 3));
            }
            #pragma unroll
            for (int nq = 0; nq < 4; ++nq) {
                int row = wcq * 64 + nq * 16 + lr;
                bq[nq] = *(const bf16x8*)(Qa + row * 64 + (((s * 4 + lg) ^ (row & 7)) << 3));
            }
            #pragma unroll
            for (int mk = 0; mk < 4; ++mk)
                #pragma unroll
                for (int nq = 0; nq < 4; ++nq)
                    acc[mk][nq] = __builtin_amdgcn_mfma_f32_16x16x32_bf16(a[mk], bq[nq], acc[mk][nq], 0, 0, 0);
        }
        __syncthreads();
    }

    // epilogue: e = expf(acc) (scale pre-folded into Q), pack fp8 e4m3, store,
    // column (q) partial sums in f32
    int k0 = kt * 128 + wrk * 64;
    int q0 = qt * 256 + wcq * 64;
    float psum[4][4];                   // [mk][r]
    #pragma unroll
    for (int mk = 0; mk < 4; ++mk) {
        float ps0 = 0.f, ps1 = 0.f, ps2 = 0.f, ps3 = 0.f;
        #pragma unroll
        for (int nq = 0; nq < 4; ++nq) {
            int q = q0 + nq * 16 + lr;
            float e0 = __expf(acc[mk][nq][0]);
            float e1 = __expf(acc[mk][nq][1]);
            float e2 = __expf(acc[mk][nq][2]);
            float e3 = __expf(acc[mk][nq][3]);
            ps0 += e0; ps1 += e1; ps2 += e2; ps3 += e3;
            int pk = 0;
            pk = __builtin_amdgcn_cvt_pk_fp8_f32(e0, e1, pk, false);
            pk = __builtin_amdgcn_cvt_pk_fp8_f32(e2, e3, pk, true);
            *(unsigned*)(E8 + ((((size_t)b << 12) + q) * 4096) + k0 + mk * 16 + lg * 4) = (unsigned)pk;
        }
        psum[mk][0] = ps0; psum[mk][1] = ps1; psum[mk][2] = ps2; psum[mk][3] = ps3;
    }
    #pragma unroll
    for (int mk = 0; mk < 4; ++mk)
        #pragma unroll
        for (int r = 0; r < 4; ++r) {
            float v = psum[mk][r];
            v += __shfl_xor(v, 1);
            v += __shfl_xor(v, 2);
            v += __shfl_xor(v, 4);
            v += __shfl_xor(v, 8);
            psum[mk][r] = v;
        }
    if (lr == 0) {
        #pragma unroll
        for (int mk = 0; mk < 4; ++mk)
            #pragma unroll
            for (int r = 0; r < 4; ++r)
                plds[wcq * 128 + wrk * 64 + mk * 16 + lg * 4 + r] = psum[mk][r];
    }
    __syncthreads();
    if (t < 128) {
        float s = plds[t] + plds[128 + t] + plds[256 + t] + plds[384 + t];
        pl[(b * 16 + qt) * 4096 + kt * 128 + t] = s;
    }
}

// k_lred: rl[b][k] = 1 / sum_qt pl[b][qt][k]   (16 q-tiles of 256)
__global__ void k_lred(const float* __restrict__ pl, float* __restrict__ rl) {
    int gid = blockIdx.x * 256 + threadIdx.x;   // 16384
    float s = 0.f;
    int b = gid >> 12, k = gid & 4095;
    #pragma unroll
    for (int qt = 0; qt < 16; ++qt) s += pl[(b * 16 + qt) * 4096 + k];
    rl[gid] = 1.0f / s;
}

// k_vn v2: Vn8[b][c][k] = fp8(VT[b][c][k] * rl[b][k] * 4096)   (2^12 exact;
// rescale keeps values in e4m3 normal range; undone by 2^-12 in k_pv epilogue)
__global__ void k_vn(const short* __restrict__ VT, const float* __restrict__ rl,
                     unsigned char* __restrict__ Vn8) {
    int gid = blockIdx.x * 256 + threadIdx.x;   // 524288
    int idx8 = gid * 8;
    int b = idx8 >> 20;
    int k = idx8 & 4095;
    bf16x8 v = *(const bf16x8*)(VT + idx8);
    const float* rb = rl + (b << 12) + k;
    f32x4 r0 = *(const f32x4*)(rb);
    f32x4 r1 = *(const f32x4*)(rb + 4);
    float f[8];
    #pragma unroll
    for (int e = 0; e < 8; ++e) {
        float rr = (e < 4) ? r0[e] : r1[e - 4];
        f[e] = bf2f(v[e]) * rr * 4096.0f;
    }
    int lo = 0, hi = 0;
    lo = __builtin_amdgcn_cvt_pk_fp8_f32(f[0], f[1], lo, false);
    lo = __builtin_amdgcn_cvt_pk_fp8_f32(f[2], f[3], lo, true);
    hi = __builtin_amdgcn_cvt_pk_fp8_f32(f[4], f[5], hi, false);
    hi = __builtin_amdgcn_cvt_pk_fp8_f32(f[6], f[7], hi, true);
    uint2 u; u.x = (unsigned)lo; u.y = (unsigned)hi;
    *(uint2*)(Vn8 + idx8) = u;
}

// ---------------- k_pv v10 (fp8): BK=128, 64q x 128c block, 4 waves of 32q x 64c,
// mfma_f32_16x16x32_fp8_fp8 (8 B/lane frags). LDS 24 KB. 8-chunk-row swizzle
// (rows are 128 B = 8 x 16B chunks). acc scaled by 2^-12 at store (Vn8 prescale).
__global__ __launch_bounds__(256) void k_pv(const unsigned char* __restrict__ E8,
                                            const unsigned char* __restrict__ Vn8,
                                            float* __restrict__ out) {
    int o = blockIdx.x;                 // 512
    int ct = o >> 8;                    // c-half
    int r = o & 255;
    int b = r >> 6, qt = r & 63;
    int t = threadIdx.x, l = t & 63, w = t >> 6;
    int wq = w >> 1, wc = w & 1;        // wave: 32 q x 64 c
    int lr = l & 15, lg = l >> 4;
    int q0 = qt * 64, c0 = ct * 128;
    __shared__ __align__(16) unsigned char Ea8[64 * 128];    // 8 KB
    __shared__ __align__(16) unsigned char Va8[128 * 128];   // 16 KB
    const unsigned char* Eg = E8 + (((size_t)b << 12) + q0) * 4096;
    const unsigned char* Vg = Vn8 + ((size_t)(b * 256 + c0)) * 4096;
    f32x4 acc[2][4] = {};

    for (int kc = 0; kc < 4096; kc += 128) {
        // E tile [64][128B]: 512 16B-chunks, 2/thread
        #pragma unroll
        for (int j = 0; j < 2; ++j) {
            int idx = j * 256 + t;
            int row = idx >> 3;
            int slot = (idx & 7) ^ (row & 7);
            gld16(Eg + kc + (size_t)row * 4096 + slot * 16, Ea8 + idx * 16);
        }
        // V tile [128][128B]: 1024 chunks, 4/thread
        #pragma unroll
        for (int j = 0; j < 4; ++j) {
            int idx = j * 256 + t;
            int row = idx >> 3;
            int slot = (idx & 7) ^ (row & 7);
            gld16(Vg + kc + (size_t)row * 4096 + slot * 16, Va8 + idx * 16);
        }
        __syncthreads();
        #pragma unroll
        for (int s = 0; s < 4; ++s) {
            int gchunk = s * 2 + (lg >> 1);
            int off8 = (lg & 1) * 8;
            long Af[2], Bf[4];
            #pragma unroll
            for (int mq = 0; mq < 2; ++mq) {
                int row = wq * 32 + mq * 16 + lr;
                Af[mq] = *(const long*)(Ea8 + row * 128 + ((gchunk ^ (row & 7)) << 4) + off8);
            }
            #pragma unroll
            for (int nc = 0; nc < 4; ++nc) {
                int row = wc * 64 + nc * 16 + lr;
                Bf[nc] = *(const long*)(Va8 + row * 128 + ((gchunk ^ (row & 7)) << 4) + off8);
            }
            #pragma unroll
            for (int mq = 0; mq < 2; ++mq)
                #pragma unroll
                for (int nc = 0; nc < 4; ++nc)
                    acc[mq][nc] = __builtin_amdgcn_mfma_f32_16x16x32_fp8_fp8(Af[mq], Bf[nc], acc[mq][nc], 0, 0, 0);
        }
        __syncthreads();
    }
    #pragma unroll
    for (int mq = 0; mq < 2; ++mq)
        #pragma unroll
        for (int nc = 0; nc < 4; ++nc) {
            int c = c0 + wc * 64 + nc * 16 + lr;
            int q = q0 + wq * 32 + mq * 16 + lg * 4;
            f32x4 oo = acc[mq][nc] * 0.000244140625f;   // 2^-12 undoes Vn8 prescale
            *(f32x4*)(out + (((size_t)b << 8) + c) * 4096 + q) = oo;
        }
}

extern "C" void kernel_launch(void* const* d_in, const int* in_sizes, int n_in,
                              void* d_out, int out_size, void* d_ws, size_t ws_size,
                              hipStream_t stream) {
    const float* x  = (const float*)d_in[0];
    const float* Wq = (const float*)d_in[1];
    const float* Wk = (const float*)d_in[2];
    const float* Wv = (const float*)d_in[3];

    char* p = (char*)d_ws;
    short* xt  = (short*)p; p += 4 * 4096 * 256 * 2;   // 8 MB
    short* Wt  = (short*)p; p += 3 * 256 * 256 * 2;    // 384 KB
    short* Qm  = (short*)p; p += 4 * 4096 * 256 * 2;
    short* Km  = (short*)p; p += 4 * 4096 * 256 * 2;
    short* VT  = (short*)p; p += 4 * 4096 * 256 * 2;
    unsigned char* E8 = (unsigned char*)p; p += (size_t)4 * 4096 * 4096 * 2; // 67 MB used
    float* pl  = (float*)p; p += 4 * 32 * 4096 * 4;            // 2 MB (16 used)
    float* rl  = (float*)p; p += 4 * 4096 * 4;                 // 64 KB
    unsigned char* Vn8 = (unsigned char*)p; p += 4 * 4096 * 256 * 2;  // 4 MB used

    float* out = (float*)d_out;

    k_prep <<<1280, 256, 0, stream>>>(x, Wq, Wk, Wv, xt, Wt);
    k_proj <<<768, 256, 0, stream>>>(xt, Wt, Qm, Km, VT);
    k_E    <<<2048, 512, 0, stream>>>(Qm, Km, E8, pl);
    k_lred <<<64,   256, 0, stream>>>(pl, rl);
    k_vn   <<<2048, 256, 0, stream>>>(VT, rl, Vn8);
    k_pv   <<<512,  256, 0, stream>>>(E8, Vn8, out);
}

// Round 24
// 145.089 us; speedup vs baseline: 3.4868x; 1.0029x over previous
//
#include <hip/hip_runtime.h>
#include <hip/hip_bf16.h>
#include <math.h>

typedef float f32x4 __attribute__((ext_vector_type(4)));
typedef short bf16x8 __attribute__((ext_vector_type(8)));
typedef short bf16x4 __attribute__((ext_vector_type(4)));

#define AS1 __attribute__((address_space(1)))
#define AS3 __attribute__((address_space(3)))

__device__ __forceinline__ short f2bf(float f) {
    unsigned u = __float_as_uint(f);
    unsigned r = (u + 0x7fffu + ((u >> 16) & 1u)) >> 16;
    return (short)r;
}
__device__ __forceinline__ float bf2f(short s) {
    return __uint_as_float(((unsigned)(unsigned short)s) << 16);
}
__device__ __forceinline__ void gld16(const void* g, void* l) {
    __builtin_amdgcn_global_load_lds((const AS1 unsigned int*)g, (AS3 unsigned int*)l, 16, 0, 0);
}

// stage a [128][64]-short tile (global row stride 256 shorts) into linear LDS
// with XOR-swizzled SOURCE (slot ^= row&7); reads use the matching swizzle.
__device__ __forceinline__ void stage128x64(const short* __restrict__ g,
                                            short* lds, int t) {
    int w = t >> 6, l = t & 63;
    #pragma unroll
    for (int j = 0; j < 4; ++j) {
        int ii = j * 4 + w;
        int row = ii * 8 + (l >> 3);
        int slot = (l & 7) ^ (row & 7);
        gld16(g + row * 256 + slot * 8, lds + ii * 512);
    }
}

// ---------------- kernel 0+1 merged: weight transpose (bid<768) + pe/x transpose
__global__ __launch_bounds__(256) void k_prep(const float* __restrict__ x,
                                              const float* __restrict__ Wq,
                                              const float* __restrict__ Wk,
                                              const float* __restrict__ Wv,
                                              short* __restrict__ xt,
                                              short* __restrict__ Wt) {
    int bidx = blockIdx.x;              // 1280 = 768 wt + 512 pe
    if (bidx < 768) {
        int wsel = bidx >> 8, n = bidx & 255, k = threadIdx.x;
        const float* W = (wsel == 0) ? Wq : (wsel == 1) ? Wk : Wv;
        Wt[(wsel * 256 + n) * 256 + k] = f2bf(W[k * 256 + n]);
        return;
    }
    int bid = bidx - 768;               // 512 = 4 b * 128 pblocks(32)
    int b = bid >> 7;
    int pb = bid & 127;
    __shared__ __align__(16) float tile[256][33];
    __shared__ __align__(16) float pew[128][32];
    __shared__ __align__(16) float peh[128];
    int t = threadIdx.x;
    const float c1 = 0.14391156f;       // ln(10000)/64
    int wbase = (pb & 1) * 32;
    int hpos = pb >> 1;
    #pragma unroll
    for (int j = 0; j < 16; ++j) {
        int idx = t + j * 256;          // < 4096
        int c = idx >> 5, pp = idx & 31;
        int i = c >> 1;
        float d = expf(-(float)i * c1);
        float arg = (float)(wbase + pp) * d;
        pew[c][pp] = (c & 1) ? cosf(arg) : sinf(arg);
    }
    if (t < 128) {
        int i = t >> 1;
        float d = expf(-(float)i * c1);
        float arg = (float)hpos * d;
        peh[t] = (t & 1) ? cosf(arg) : sinf(arg);
    }
    int p0 = pb * 32;
    #pragma unroll
    for (int j = 0; j < 32; ++j) {
        int c = j * 8 + (t >> 5);
        int pp = t & 31;
        tile[c][pp] = x[((b * 256 + c) << 12) + p0 + pp];
    }
    __syncthreads();
    int pp = t >> 3, cseg = t & 7;
    int p = p0 + pp;
    short* dst = xt + (((b << 12) + p) << 8) + (cseg << 5);
    #pragma unroll
    for (int j = 0; j < 4; ++j) {
        bf16x8 v;
        #pragma unroll
        for (int e = 0; e < 8; ++e) {
            int c = cseg * 32 + j * 8 + e;
            float pe = (c < 128) ? pew[c][pp] : peh[c - 128];
            v[e] = f2bf(tile[c][pp] + pe);
        }
        ((bf16x8*)dst)[j] = v;
    }
}

// ---------------- kernel 2: LDS-staged projections (m97-style K-loop).
// Q = (xt@Wq)*0.0625, K = xt@Wk, V^T.
__global__ __launch_bounds__(256, 4) void k_proj(const short* __restrict__ xt,
                                                 const short* __restrict__ Wt,
                                                 short* __restrict__ Q,
                                                 short* __restrict__ K,
                                                 short* __restrict__ VT) {
    int id = blockIdx.x;                // 768 = 4b * 32mt * 2nt * 3w
    int wsel = id % 3; id /= 3;
    int nt = id & 1;  id >>= 1;
    int mt = id & 31; int b = id >> 5;
    int t = threadIdx.x, l = t & 63, w = t >> 6;
    int lr = l & 15, lg = l >> 4;
    int wr = w >> 1, wc = w & 1;        // wave sub-tile: 64m x 64n
    __shared__ __align__(16) short Xa[128 * 64];
    __shared__ __align__(16) short Wa[128 * 64];
    const short* Xg = xt + (((size_t)b << 12) + mt * 128) * 256;
    const short* Wg = Wt + ((size_t)wsel * 256 + nt * 128) * 256;
    f32x4 acc[4][4] = {};

    #pragma unroll
    for (int ks = 0; ks < 4; ++ks) {
        stage128x64(Xg + ks * 64, Xa, t);
        stage128x64(Wg + ks * 64, Wa, t);
        __syncthreads();
        #pragma unroll
        for (int s = 0; s < 2; ++s) {
            bf16x8 af[4], bw[4];
            #pragma unroll
            for (int ms = 0; ms < 4; ++ms) {
                int row = wr * 64 + ms * 16 + lr;
                af[ms] = *(const bf16x8*)(Xa + row * 64 + (((s * 4 + lg) ^ (row & 7)) << 3));
            }
            #pragma unroll
            for (int fn = 0; fn < 4; ++fn) {
                int row = wc * 64 + fn * 16 + lr;
                bw[fn] = *(const bf16x8*)(Wa + row * 64 + (((s * 4 + lg) ^ (row & 7)) << 3));
            }
            #pragma unroll
            for (int ms = 0; ms < 4; ++ms)
                #pragma unroll
                for (int fn = 0; fn < 4; ++fn)
                    acc[ms][fn] = __builtin_amdgcn_mfma_f32_16x16x32_bf16(af[ms], bw[fn], acc[ms][fn], 0, 0, 0);
        }
        __syncthreads();
    }

    int m0 = mt * 128 + wr * 64;
    int n0 = nt * 128 + wc * 64;
    if (wsel < 2) {
        float scl = (wsel == 0) ? 0.0625f : 1.0f;
        short* dst = (wsel == 0) ? Q : K;
        #pragma unroll
        for (int ms = 0; ms < 4; ++ms)
            #pragma unroll
            for (int fn = 0; fn < 4; ++fn)
                #pragma unroll
                for (int r = 0; r < 4; ++r) {
                    int m = m0 + ms * 16 + lg * 4 + r;
                    int n = n0 + fn * 16 + lr;
                    dst[((b << 12) + m) * 256 + n] = f2bf(acc[ms][fn][r] * scl);
                }
    } else {
        #pragma unroll
        for (int ms = 0; ms < 4; ++ms)
            #pragma unroll
            for (int fn = 0; fn < 4; ++fn) {
                int n = n0 + fn * 16 + lr;
                int m = m0 + ms * 16 + lg * 4;
                bf16x4 v;
                #pragma unroll
                for (int r = 0; r < 4; ++r) v[r] = f2bf(acc[ms][fn][r]);
                *(bf16x4*)(VT + ((b * 256 + n) << 12) + m) = v;
            }
    }
}

// ---------------- k_E (round-22 proven): bf16 QK 128k x 256q loop; epilogue packs
// E to fp8 e4m3 via v_cvt_pk_fp8_f32 (E stream halved). fp8 QK was falsified
// (absmax 0.0625 > 0.05625): S errors pass through exp before normalization.
__global__ __launch_bounds__(512) void k_E(const short* __restrict__ Qm,
                                           const short* __restrict__ Km,
                                           unsigned char* __restrict__ E8,
                                           float* __restrict__ pl) {
    int o = blockIdx.x;                 // 2048 = 4b * 32kt * 16qt
    int bid = (o & 7) * 256 + (o >> 3); // XCD swizzle (2048 % 8 == 0, bijective)
    int qt = bid & 15, kt = (bid >> 4) & 31, b = bid >> 9;
    int t = threadIdx.x, l = t & 63;
    int w = t >> 6;
    int wrk = w & 1, wcq = w >> 1;      // wave sub-tile: 64k x 64q (2 x 4 waves)
    int lr = l & 15, lg = l >> 4;
    __shared__ __align__(16) short Ka[128 * 64];   // 16 KB
    __shared__ __align__(16) short Qa[256 * 64];   // 32 KB
    __shared__ float plds[4 * 128];                // 2 KB
    const short* Kg = Km + (((size_t)b << 12) + kt * 128) * 256;
    const short* Qg = Qm + (((size_t)b << 12) + qt * 256) * 256;
    f32x4 acc[4][4] = {};

    #pragma unroll
    for (int ks = 0; ks < 4; ++ks) {
        #pragma unroll
        for (int j = 0; j < 2; ++j) {
            int idx = j * 512 + t;
            int row = idx >> 3;
            int slot = (idx & 7) ^ (row & 7);
            gld16(Kg + ks * 64 + row * 256 + slot * 8, Ka + idx * 8);
        }
        #pragma unroll
        for (int j = 0; j < 4; ++j) {
            int idx = j * 512 + t;
            int row = idx >> 3;
            int slot = (idx & 7) ^ (row & 7);
            gld16(Qg + ks * 64 + row * 256 + slot * 8, Qa + idx * 8);
        }
        __syncthreads();
        #pragma unroll
        for (int s = 0; s < 2; ++s) {
            bf16x8 a[4], bq[4];
            #pragma unroll
            for (int mk = 0; mk < 4; ++mk) {
                int row = wrk * 64 + mk * 16 + lr;
                a[mk] = *(const bf16x8*)(Ka + row * 64 + (((s * 4 + lg) ^ (row & 7)) << 3));
            }
            #pragma unroll
            for (int nq = 0; nq < 4; ++nq) {
                int row = wcq * 64 + nq * 16 + lr;
                bq[nq] = *(const bf16x8*)(Qa + row * 64 + (((s * 4 + lg) ^ (row & 7)) << 3));
            }
            #pragma unroll
            for (int mk = 0; mk < 4; ++mk)
                #pragma unroll
                for (int nq = 0; nq < 4; ++nq)
                    acc[mk][nq] = __builtin_amdgcn_mfma_f32_16x16x32_bf16(a[mk], bq[nq], acc[mk][nq], 0, 0, 0);
        }
        __syncthreads();
    }

    // epilogue: e = expf(acc) (scale pre-folded into Q), pack fp8 e4m3, store,
    // column (q) partial sums in f32
    int k0 = kt * 128 + wrk * 64;
    int q0 = qt * 256 + wcq * 64;
    float psum[4][4];                   // [mk][r]
    #pragma unroll
    for (int mk = 0; mk < 4; ++mk) {
        float ps0 = 0.f, ps1 = 0.f, ps2 = 0.f, ps3 = 0.f;
        #pragma unroll
        for (int nq = 0; nq < 4; ++nq) {
            int q = q0 + nq * 16 + lr;
            float e0 = __expf(acc[mk][nq][0]);
            float e1 = __expf(acc[mk][nq][1]);
            float e2 = __expf(acc[mk][nq][2]);
            float e3 = __expf(acc[mk][nq][3]);
            ps0 += e0; ps1 += e1; ps2 += e2; ps3 += e3;
            int pk = 0;
            pk = __builtin_amdgcn_cvt_pk_fp8_f32(e0, e1, pk, false);
            pk = __builtin_amdgcn_cvt_pk_fp8_f32(e2, e3, pk, true);
            *(unsigned*)(E8 + ((((size_t)b << 12) + q) * 4096) + k0 + mk * 16 + lg * 4) = (unsigned)pk;
        }
        psum[mk][0] = ps0; psum[mk][1] = ps1; psum[mk][2] = ps2; psum[mk][3] = ps3;
    }
    #pragma unroll
    for (int mk = 0; mk < 4; ++mk)
        #pragma unroll
        for (int r = 0; r < 4; ++r) {
            float v = psum[mk][r];
            v += __shfl_xor(v, 1);
            v += __shfl_xor(v, 2);
            v += __shfl_xor(v, 4);
            v += __shfl_xor(v, 8);
            psum[mk][r] = v;
        }
    if (lr == 0) {
        #pragma unroll
        for (int mk = 0; mk < 4; ++mk)
            #pragma unroll
            for (int r = 0; r < 4; ++r)
                plds[wcq * 128 + wrk * 64 + mk * 16 + lg * 4 + r] = psum[mk][r];
    }
    __syncthreads();
    if (t < 128) {
        float s = plds[t] + plds[128 + t] + plds[256 + t] + plds[384 + t];
        pl[(b * 16 + qt) * 4096 + kt * 128 + t] = s;
    }
}

// k_lred: rl[b][k] = 1 / sum_qt pl[b][qt][k]   (16 q-tiles of 256)
__global__ void k_lred(const float* __restrict__ pl, float* __restrict__ rl) {
    int gid = blockIdx.x * 256 + threadIdx.x;   // 16384
    float s = 0.f;
    int b = gid >> 12, k = gid & 4095;
    #pragma unroll
    for (int qt = 0; qt < 16; ++qt) s += pl[(b * 16 + qt) * 4096 + k];
    rl[gid] = 1.0f / s;
}

// k_vn: Vn8[b][c][k] = fp8(VT[b][c][k] * rl[b][k] * 4096)   (2^12 exact prescale;
// keeps values in e4m3 normal range; undone by 2^-12 in k_pv epilogue)
__global__ void k_vn(const short* __restrict__ VT, const float* __restrict__ rl,
                     unsigned char* __restrict__ Vn8) {
    int gid = blockIdx.x * 256 + threadIdx.x;   // 524288
    int idx8 = gid * 8;
    int b = idx8 >> 20;
    int k = idx8 & 4095;
    bf16x8 v = *(const bf16x8*)(VT + idx8);
    const float* rb = rl + (b << 12) + k;
    f32x4 r0 = *(const f32x4*)(rb);
    f32x4 r1 = *(const f32x4*)(rb + 4);
    float f[8];
    #pragma unroll
    for (int e = 0; e < 8; ++e) {
        float rr = (e < 4) ? r0[e] : r1[e - 4];
        f[e] = bf2f(v[e]) * rr * 4096.0f;
    }
    int lo = 0, hi = 0;
    lo = __builtin_amdgcn_cvt_pk_fp8_f32(f[0], f[1], lo, false);
    lo = __builtin_amdgcn_cvt_pk_fp8_f32(f[2], f[3], lo, true);
    hi = __builtin_amdgcn_cvt_pk_fp8_f32(f[4], f[5], hi, false);
    hi = __builtin_amdgcn_cvt_pk_fp8_f32(f[6], f[7], hi, true);
    uint2 u; u.x = (unsigned)lo; u.y = (unsigned)hi;
    *(uint2*)(Vn8 + idx8) = u;
}

// ---------------- k_pv (round-22 proven, fp8): BK=128, 64q x 128c block,
// 4 waves of 32q x 64c, mfma fp8, 24 KB LDS, 8-chunk-row swizzle, pair mapping.
__global__ __launch_bounds__(256) void k_pv(const unsigned char* __restrict__ E8,
                                            const unsigned char* __restrict__ Vn8,
                                            float* __restrict__ out) {
    int o = blockIdx.x;                 // 512
    int ct = o >> 8;                    // c-half
    int r = o & 255;
    int b = r >> 6, qt = r & 63;
    int t = threadIdx.x, l = t & 63, w = t >> 6;
    int wq = w >> 1, wc = w & 1;        // wave: 32 q x 64 c
    int lr = l & 15, lg = l >> 4;
    int q0 = qt * 64, c0 = ct * 128;
    __shared__ __align__(16) unsigned char Ea8[64 * 128];    // 8 KB
    __shared__ __align__(16) unsigned char Va8[128 * 128];   // 16 KB
    const unsigned char* Eg = E8 + (((size_t)b << 12) + q0) * 4096;
    const unsigned char* Vg = Vn8 + ((size_t)(b * 256 + c0)) * 4096;
    f32x4 acc[2][4] = {};

    for (int kc = 0; kc < 4096; kc += 128) {
        #pragma unroll
        for (int j = 0; j < 2; ++j) {
            int idx = j * 256 + t;
            int row = idx >> 3;
            int slot = (idx & 7) ^ (row & 7);
            gld16(Eg + kc + (size_t)row * 4096 + slot * 16, Ea8 + idx * 16);
        }
        #pragma unroll
        for (int j = 0; j < 4; ++j) {
            int idx = j * 256 + t;
            int row = idx >> 3;
            int slot = (idx & 7) ^ (row & 7);
            gld16(Vg + kc + (size_t)row * 4096 + slot * 16, Va8 + idx * 16);
        }
        __syncthreads();
        #pragma unroll
        for (int s = 0; s < 4; ++s) {
            int gchunk = s * 2 + (lg >> 1);
            int off8 = (lg & 1) * 8;
            long Af[2], Bf[4];
            #pragma unroll
            for (int mq = 0; mq < 2; ++mq) {
                int row = wq * 32 + mq * 16 + lr;
                Af[mq] = *(const long*)(Ea8 + row * 128 + ((gchunk ^ (row & 7)) << 4) + off8);
            }
            #pragma unroll
            for (int nc = 0; nc < 4; ++nc) {
                int row = wc * 64 + nc * 16 + lr;
                Bf[nc] = *(const long*)(Va8 + row * 128 + ((gchunk ^ (row & 7)) << 4) + off8);
            }
            #pragma unroll
            for (int mq = 0; mq < 2; ++mq)
                #pragma unroll
                for (int nc = 0; nc < 4; ++nc)
                    acc[mq][nc] = __builtin_amdgcn_mfma_f32_16x16x32_fp8_fp8(Af[mq], Bf[nc], acc[mq][nc], 0, 0, 0);
        }
        __syncthreads();
    }
    #pragma unroll
    for (int mq = 0; mq < 2; ++mq)
        #pragma unroll
        for (int nc = 0; nc < 4; ++nc) {
            int c = c0 + wc * 64 + nc * 16 + lr;
            int q = q0 + wq * 32 + mq * 16 + lg * 4;
            f32x4 oo = acc[mq][nc] * 0.000244140625f;   // 2^-12 undoes Vn8 prescale
            *(f32x4*)(out + (((size_t)b << 8) + c) * 4096 + q) = oo;
        }
}

extern "C" void kernel_launch(void* const* d_in, const int* in_sizes, int n_in,
                              void* d_out, int out_size, void* d_ws, size_t ws_size,
                              hipStream_t stream) {
    const float* x  = (const float*)d_in[0];
    const float* Wq = (const float*)d_in[1];
    const float* Wk = (const float*)d_in[2];
    const float* Wv = (const float*)d_in[3];

    char* p = (char*)d_ws;
    short* xt  = (short*)p; p += 4 * 4096 * 256 * 2;   // 8 MB
    short* Wt  = (short*)p; p += 3 * 256 * 256 * 2;    // 384 KB
    short* Qm  = (short*)p; p += 4 * 4096 * 256 * 2;
    short* Km  = (short*)p; p += 4 * 4096 * 256 * 2;
    short* VT  = (short*)p; p += 4 * 4096 * 256 * 2;
    unsigned char* E8 = (unsigned char*)p; p += (size_t)4 * 4096 * 4096; // 67 MB
    float* pl  = (float*)p; p += 4 * 16 * 4096 * 4;            // 1 MB
    float* rl  = (float*)p; p += 4 * 4096 * 4;                 // 64 KB
    unsigned char* Vn8 = (unsigned char*)p; p += 4 * 4096 * 256;  // 4 MB

    float* out = (float*)d_out;

    k_prep <<<1280, 256, 0, stream>>>(x, Wq, Wk, Wv, xt, Wt);
    k_proj <<<768, 256, 0, stream>>>(xt, Wt, Qm, Km, VT);
    k_E    <<<2048, 512, 0, stream>>>(Qm, Km, E8, pl);
    k_lred <<<64,   256, 0, stream>>>(pl, rl);
    k_vn   <<<2048, 256, 0, stream>>>(VT, rl, Vn8);
    k_pv   <<<512,  256, 0, stream>>>(E8, Vn8, out);
}